// Round 1
// baseline (1937.099 us; speedup 1.0000x reference)
//
#include <hip/hip_runtime.h>
#include <hip/hip_bf16.h>

// Problem dims (fixed by reference setup_inputs):
// B=2, S=2048, H=4096, NH=32, NS=100, D=64
#define Bq 2
#define Sq 2048
#define Hq 4096
#define NHq 32
#define NSq 100
#define Dq 64

// ---------------------------------------------------------------------------
// K1: entropy of head-averaged primary attention + gate (with veto) -> ws
// One block per (b,s). Reads 32 contiguous rows of 2048 floats (8 KB each),
// accumulates across heads in registers (2 float4/thread), then log+reduce.
// Memory-bound: streams the full 1.07 GB paw tensor once, coalesced.
// ---------------------------------------------------------------------------
__global__ __launch_bounds__(256) void k_entropy_gate(
    const float* __restrict__ paw,
    const float* __restrict__ gw1p,
    const float* __restrict__ gbp,
    float* __restrict__ gate_ws) {
  const int bs = blockIdx.x;            // 0..B*S-1
  const int b = bs >> 11;               // /2048
  const int s = bs & 2047;
  const int t = threadIdx.x;

  const float4* base = reinterpret_cast<const float4*>(paw);
  // float4 index of row start for head h: ((b*32+h)*2048 + s) * 512
  long rbase = ((long)(b * NHq) * Sq + s) * (Sq / 4);
  const long hstep = (long)Sq * (Sq / 4);   // per-head stride in float4

  float4 a0 = make_float4(0.f, 0.f, 0.f, 0.f);
  float4 a1 = make_float4(0.f, 0.f, 0.f, 0.f);
#pragma unroll
  for (int h = 0; h < NHq; ++h) {
    const float4 v0 = base[rbase + t];
    const float4 v1 = base[rbase + 256 + t];
    a0.x += v0.x; a0.y += v0.y; a0.z += v0.z; a0.w += v0.w;
    a1.x += v1.x; a1.y += v1.y; a1.z += v1.z; a1.w += v1.w;
    rbase += hstep;
  }

  // entropy terms: y = avg, term = -y*log(y+1e-10)
  const float inv = 1.f / 32.f;
  float e = 0.f;
  {
    float y;
    y = a0.x * inv; e -= y * __logf(y + 1e-10f);
    y = a0.y * inv; e -= y * __logf(y + 1e-10f);
    y = a0.z * inv; e -= y * __logf(y + 1e-10f);
    y = a0.w * inv; e -= y * __logf(y + 1e-10f);
    y = a1.x * inv; e -= y * __logf(y + 1e-10f);
    y = a1.y * inv; e -= y * __logf(y + 1e-10f);
    y = a1.z * inv; e -= y * __logf(y + 1e-10f);
    y = a1.w * inv; e -= y * __logf(y + 1e-10f);
  }
  // wave (64) reduce, then cross-wave via LDS
#pragma unroll
  for (int off = 32; off > 0; off >>= 1) e += __shfl_down(e, off, 64);
  __shared__ float red[4];
  if ((t & 63) == 0) red[t >> 6] = e;
  __syncthreads();
  if (t == 0) {
    const float ent = red[0] + red[1] + red[2] + red[3];
    float g = 1.f / (1.f + __expf(-(gw1p[0] * ent + gbp[0])));
    if (ent < 0.5f) g = 0.f;
    else if (ent > 2.0f) g = fminf(g, 0.8f);
    gate_ws[bs] = g;
  }
}

// ---------------------------------------------------------------------------
// K2: query projection + scores + softmax, gate folded into stored weights.
// One block per (b,s) row. hs row (16 KB) staged in LDS; W_q streamed from
// L2/L1 (each wave keeps 64 row-streams L1-resident).
// ---------------------------------------------------------------------------
__global__ __launch_bounds__(256) void k_query_softmax(
    const float* __restrict__ hs,
    const float* __restrict__ Wq,
    const float* __restrict__ ak,
    const float* __restrict__ rel,
    const float* __restrict__ gate_ws,
    float* __restrict__ attn_ws) {
  const int bs = blockIdx.x;   // row 0..4095
  const int t = threadIdx.x;

  __shared__ float4 shs4[Hq / 4];       // 16 KB
  __shared__ float qred[4][Dq];
  __shared__ float sq[Dq];
  __shared__ float ssc[128];

  const float4* hs4 = reinterpret_cast<const float4*>(hs) + (long)bs * (Hq / 4);
#pragma unroll
  for (int j = 0; j < 4; ++j) shs4[t + j * 256] = hs4[t + j * 256];
  if (t >= 100 && t < 128) ssc[t] = -1e30f;   // pad for softmax
  __syncthreads();

  // query[d] : 4 partial dot-products of length 1024 each
  const int d = t & 63;
  const int part = t >> 6;
  {
    const float4* wq4 = reinterpret_cast<const float4*>(Wq) + (long)d * (Hq / 4) + part * 256;
    const float4* sh = shs4 + part * 256;
    float acc = 0.f;
#pragma unroll 4
    for (int i = 0; i < 256; ++i) {
      const float4 w = wq4[i];
      const float4 x = sh[i];
      acc += w.x * x.x + w.y * x.y + w.z * x.z + w.w * x.w;
    }
    qred[part][d] = acc;
  }
  __syncthreads();
  if (t < Dq) sq[t] = qred[0][t] + qred[1][t] + qred[2][t] + qred[3][t];
  __syncthreads();

  // scores for slot n = t (t < 100)
  if (t < NSq) {
    float a = 0.f;
    const float* akn = ak + t * Dq;
#pragma unroll
    for (int dd = 0; dd < Dq; ++dd) a += sq[dd] * akn[dd];
    ssc[t] = a * 0.125f + __logf(rel[t] + 1e-10f);
  }
  __syncthreads();

  // softmax over 100 slots, wave 0 only (2 values per lane), gate folded in
  if (t < 64) {
    float s0 = ssc[t];
    float s1 = ssc[t + 64];
    float m = fmaxf(s0, s1);
#pragma unroll
    for (int off = 1; off < 64; off <<= 1) m = fmaxf(m, __shfl_xor(m, off, 64));
    float p0 = __expf(s0 - m);
    float p1 = __expf(s1 - m);
    float sum = p0 + p1;
#pragma unroll
    for (int off = 1; off < 64; off <<= 1) sum += __shfl_xor(sum, off, 64);
    const float scale = gate_ws[bs] / sum;   // gate folded in here
    float* arow = attn_ws + (long)bs * NSq;
    arow[t] = p0 * scale;
    if (t + 64 < NSq) arow[t + 64] = p1 * scale;
  }
}

// ---------------------------------------------------------------------------
// K3: fused = pao + sum_n attn_ws[row][n] * aux_values[n][:]
// Block = 16 rows x 1024 columns (one float4/thread/row). aux_values stays
// L2-resident; read 400 KB per block instead of 1.6 MB per row.
// ---------------------------------------------------------------------------
__global__ __launch_bounds__(256) void k_aux_fuse(
    const float* __restrict__ av,
    const float* __restrict__ pao,
    const float* __restrict__ attn_ws,
    float* __restrict__ out) {
  const int ht = blockIdx.x;     // 0..3   (h tile of 1024)
  const int rb = blockIdx.y;     // 0..255 (row block of 16)
  const int t = threadIdx.x;
  const int r0 = rb * 16;

  __shared__ float sattn[16 * NSq];
  for (int idx = t; idx < 16 * NSq; idx += 256)
    sattn[idx] = attn_ws[(long)r0 * NSq + idx];
  __syncthreads();

  const int c4 = ht * 256 + t;   // float4 column 0..1023
  const float4* av4 = reinterpret_cast<const float4*>(av);

  float4 acc[16];
#pragma unroll
  for (int r = 0; r < 16; ++r) acc[r] = make_float4(0.f, 0.f, 0.f, 0.f);

  for (int n = 0; n < NSq; ++n) {
    const float4 v = av4[(long)n * (Hq / 4) + c4];
#pragma unroll
    for (int r = 0; r < 16; ++r) {
      const float wv = sattn[r * NSq + n];
      acc[r].x += wv * v.x;
      acc[r].y += wv * v.y;
      acc[r].z += wv * v.z;
      acc[r].w += wv * v.w;
    }
  }

  const float4* pao4 = reinterpret_cast<const float4*>(pao);
  float4* out4 = reinterpret_cast<float4*>(out);
#pragma unroll
  for (int r = 0; r < 16; ++r) {
    const long o = (long)(r0 + r) * (Hq / 4) + c4;
    const float4 p = pao4[o];
    float4 x;
    x.x = p.x + acc[r].x;
    x.y = p.y + acc[r].y;
    x.z = p.z + acc[r].z;
    x.w = p.w + acc[r].w;
    out4[o] = x;
  }
}

extern "C" void kernel_launch(void* const* d_in, const int* in_sizes, int n_in,
                              void* d_out, int out_size, void* d_ws, size_t ws_size,
                              hipStream_t stream) {
  const float* hs  = (const float*)d_in[0];   // [2,2048,4096]
  const float* pao = (const float*)d_in[1];   // [2,2048,4096]
  const float* paw = (const float*)d_in[2];   // [2,32,2048,2048]
  const float* rel = (const float*)d_in[3];   // [100]
  const float* Wq  = (const float*)d_in[4];   // [64,4096]
  const float* ak  = (const float*)d_in[5];   // [100,64]
  const float* av  = (const float*)d_in[6];   // [100,4096]
  const float* gw1 = (const float*)d_in[7];   // scalar
  const float* gb  = (const float*)d_in[8];   // scalar
  float* out = (float*)d_out;

  float* gate_ws = (float*)d_ws;              // 4096 floats
  float* attn_ws = gate_ws + Bq * Sq;         // 4096*100 floats (gate folded in)

  k_entropy_gate<<<Bq * Sq, 256, 0, stream>>>(paw, gw1, gb, gate_ws);
  k_query_softmax<<<Bq * Sq, 256, 0, stream>>>(hs, Wq, ak, rel, gate_ws, attn_ws);
  k_aux_fuse<<<dim3(4, 256), 256, 0, stream>>>(av, pao, attn_ws, out);
}